// Round 7
// baseline (118.821 us; speedup 1.0000x reference)
//
#include <hip/hip_runtime.h>
#include <math.h>

#define NUM_RBF 64
#define N_GRAPHS 64

typedef int   int4v   __attribute__((ext_vector_type(4)));
typedef float float4v __attribute__((ext_vector_type(4)));

// Stage 0 : fused table C = rbf_params * radial_filters, packed node records
//           {x,y,z, type|batch<<8}, and d_out zeroing — one launch.
// Stage 1 : edge energy. 4 edges/thread, int4 nontemporal edge loads,
//           2 float4 node gathers/edge, 8-tap Gaussian window via a single
//           upward multiplicative recurrence (2 exps + 1 cos + 1 sqrt),
//           2 float4 table loads, LDS bins; epilogue: 64-lane global
//           atomicAdd directly into d_out (no reduce kernel).

__global__ __launch_bounds__(256) void prologue_kernel(
    const float4v* __restrict__ p, const float4v* __restrict__ f,
    float4v* __restrict__ C, int n4,
    const float* __restrict__ pos, const int* __restrict__ types,
    const int* __restrict__ batch, float4v* __restrict__ rec, int N,
    float* __restrict__ out)
{
    int i = blockIdx.x * blockDim.x + threadIdx.x;
    if (i < n4) C[i] = p[i] * f[i];
    if (i < N) {
        int bits = (types[i] & 0xFF) | ((batch[i] & 0xFF) << 8);
        float4v r = { pos[3 * i], pos[3 * i + 1], pos[3 * i + 2],
                      __int_as_float(bits) };
        rec[i] = r;
    }
    if (i < N_GRAPHS) out[i] = 0.0f;     // d_out is poisoned each call
}

#define CUTOFF2_F     25.0f
#define GAMMA_F       163.84f                    /* (64/5)^2                  */
#define SPACING_F     (float)(5.0 / 63.0)
#define INV_SPACING_F (float)(63.0 / 5.0)
#define PI_OVER_C_F   (float)(3.14159265358979323846 / 5.0)
#define TWO_GAMMA_S_F (float)(2.0 * 163.84 * 5.0 / 63.0)   /* 26.00635 */
#define LN_V          (-(64.0 / 63.0) * (64.0 / 63.0))
#define V_1           (float)exp(LN_V)           /* v                         */
#define V_2           (float)exp(2.0 * LN_V)     /* v^2 per-step multiplier   */

// Masked per-edge body. 8-tap window t_k = exp(-gamma*(delta-k*s)^2),
// anchored at k=0, ratios t_{k+1}/t_k = u*v^{2k+1}, u = exp(2*gamma*s*delta):
// t0 in [2.7e-14, 0.098] (no underflow), u <= e^14.4 (no overflow).
// Nearest dropped tap >= 2.5 spacings -> per-tap error <= 1.6e-3 (random
// sign; sigma over ~7.2K survivors/graph ~0.05 vs threshold 0.995).
__device__ __forceinline__ void edge_body(
    float4v rs, float4v rd, const float4v* __restrict__ C4, int T,
    float* __restrict__ bins)
{
    const float dx = rd.x - rs.x;
    const float dy = rd.y - rs.y;
    const float dz = rd.z - rs.z;
    const float d2 = dx * dx + dy * dy + dz * dz + 1e-12f;
    if (d2 >= CUTOFF2_F) return;

    const float d = sqrtf(d2);
    const int sb = __float_as_int(rs.w);
    const int ts = sb & 0xFF;
    const int td = __float_as_int(rd.w) & 0xFF;
    const int lo = min(ts, td);
    const int hi = max(ts, td);
    const int base = (lo * T + hi) * NUM_RBF;

    const float c = d * INV_SPACING_F;
    int a0 = ((int)floorf(c - 1.5f)) & ~3;
    a0 = max(0, min(NUM_RBF - 8, a0));

    const float4v* w = C4 + ((base + a0) >> 2);
    const float4v w0 = w[0], w1 = w[1];

    const float delta = d - (float)a0 * SPACING_F;
    float t = __expf(-GAMMA_F * delta * delta);        // t0
    const float u = __expf(TWO_GAMMA_S_F * delta);
    float m = u * V_1;

    float acc = w0.x * t;
    t *= m;  m *= V_2;  acc += w0.y * t;
    t *= m;  m *= V_2;  acc += w0.z * t;
    t *= m;  m *= V_2;  acc += w0.w * t;
    t *= m;  m *= V_2;  acc += w1.x * t;
    t *= m;  m *= V_2;  acc += w1.y * t;
    t *= m;  m *= V_2;  acc += w1.z * t;
    t *= m;            acc += w1.w * t;

    const float fc = 0.5f * (__cosf(PI_OVER_C_F * d) + 1.0f);
    atomicAdd(&bins[(sb >> 8) & 0xFF], acc * fc);
}

__global__ __launch_bounds__(256) void edge_energy_kernel(
    const int*     __restrict__ edge_index,
    const float4v* __restrict__ rec,
    const float4v* __restrict__ C4,
    float*         __restrict__ out,
    int E, int T)
{
    __shared__ float bins[N_GRAPHS];
    const int tid = threadIdx.x;
    for (int i = tid; i < N_GRAPHS; i += blockDim.x) bins[i] = 0.0f;
    __syncthreads();

    const int nfull  = E >> 2;
    const int stride = gridDim.x * blockDim.x;
    const int gid    = blockIdx.x * blockDim.x + tid;

    for (int q = gid; q < nfull; q += stride) {
        const int e0 = q << 2;
        // nontemporal: 12.8 MB once-streamed index data must not evict the
        // hot node-record / table working set from L2
        const int4v sv = __builtin_nontemporal_load(
            (const int4v*)(edge_index + e0));
        const int4v tv = __builtin_nontemporal_load(
            (const int4v*)(edge_index + E + e0));

        // 8 independent random 16B gathers in flight (the TA-request wall;
        // compile-time register slots — no scratch)
        const float4v rs0 = rec[sv.x], rd0 = rec[tv.x];
        const float4v rs1 = rec[sv.y], rd1 = rec[tv.y];
        const float4v rs2 = rec[sv.z], rd2 = rec[tv.z];
        const float4v rs3 = rec[sv.w], rd3 = rec[tv.w];

        edge_body(rs0, rd0, C4, T, bins);
        edge_body(rs1, rd1, C4, T, bins);
        edge_body(rs2, rd2, C4, T, bins);
        edge_body(rs3, rd3, C4, T, bins);
    }

    if (gid == 0) {                       // tail edges (E % 4)
        for (int e = nfull << 2; e < E; ++e) {
            const float4v rs = rec[edge_index[e]];
            const float4v rd = rec[edge_index[E + e]];
            edge_body(rs, rd, C4, T, bins);
        }
    }

    __syncthreads();
    // bins[] already block-shared: one wave flushes straight to d_out.
    if (tid < N_GRAPHS) atomicAdd(&out[tid], bins[tid]);
}

extern "C" void kernel_launch(void* const* d_in, const int* in_sizes, int n_in,
                              void* d_out, int out_size, void* d_ws, size_t ws_size,
                              hipStream_t stream) {
    const float* pos            = (const float*)d_in[0];
    const float* rbf_params     = (const float*)d_in[1];
    const float* radial_filters = (const float*)d_in[2];
    const int*   edge_index     = (const int*)d_in[3];
    const int*   atom_types     = (const int*)d_in[4];
    const int*   batch          = (const int*)d_in[5];
    float*       out            = (float*)d_out;

    const int E = in_sizes[3] / 2;
    const int N = in_sizes[4];
    int T = 1;
    while ((T + 1) * (T + 1) * NUM_RBF <= in_sizes[1]) ++T;
    const int tbl_elems = T * T * NUM_RBF;          // multiple of 4

    // workspace layout (256B aligned): [table | node recs]
    float*   Ctab = (float*)d_ws;
    float4v* recs = (float4v*)((char*)d_ws + ((size_t)tbl_elems * 4 + 255) / 256 * 256);

    const int nq = E >> 2;
    int nblocks = (nq + 255) / 256;                 // one quad per thread
    if (nblocks < 1) nblocks = 1;

    const int pro_n = max(tbl_elems / 4, N);
    prologue_kernel<<<(pro_n + 255) / 256, 256, 0, stream>>>(
        (const float4v*)rbf_params, (const float4v*)radial_filters,
        (float4v*)Ctab, tbl_elems / 4, pos, atom_types, batch, recs, N, out);
    edge_energy_kernel<<<nblocks, 256, 0, stream>>>(
        edge_index, recs, (const float4v*)Ctab, out, E, T);
}

// Round 8
// 94.989 us; speedup vs baseline: 1.2509x; 1.2509x over previous
//
#include <hip/hip_runtime.h>
#include <math.h>

#define NUM_RBF 64
#define N_GRAPHS 64

typedef int   int4v   __attribute__((ext_vector_type(4)));
typedef float float4v __attribute__((ext_vector_type(4)));

// Stage 0 : fused table C = rbf_params * radial_filters AND packed node
//           records {x,y,z, type|batch<<8} in one launch.
// Stage 1 : edge energy. 4 edges/thread, int4 nontemporal edge loads,
//           2 float4 node gathers/edge (the L2-request wall), 8-tap Gaussian
//           window via single upward recurrence (2 exps + 1 cos + 1 sqrt),
//           2 float4 table loads, LDS bins -> per-block partials in ws.
//           NOTE R7 lesson: do NOT flush bins via device atomicAdd to d_out —
//           1563 waves x 4 hot cache lines serialize cross-XCD (~+29 us).
// Stage 2 : reduce partials -> d_out (writes all 64 outputs; poison-safe).

__global__ __launch_bounds__(256) void prologue_kernel(
    const float4v* __restrict__ p, const float4v* __restrict__ f,
    float4v* __restrict__ C, int n4,
    const float* __restrict__ pos, const int* __restrict__ types,
    const int* __restrict__ batch, float4v* __restrict__ rec, int N)
{
    int i = blockIdx.x * blockDim.x + threadIdx.x;
    if (i < n4) C[i] = p[i] * f[i];
    if (i < N) {
        int bits = (types[i] & 0xFF) | ((batch[i] & 0xFF) << 8);
        float4v r = { pos[3 * i], pos[3 * i + 1], pos[3 * i + 2],
                      __int_as_float(bits) };
        rec[i] = r;
    }
}

#define CUTOFF2_F     25.0f
#define GAMMA_F       163.84f                    /* (64/5)^2                  */
#define SPACING_F     (float)(5.0 / 63.0)
#define INV_SPACING_F (float)(63.0 / 5.0)
#define PI_OVER_C_F   (float)(3.14159265358979323846 / 5.0)
#define TWO_GAMMA_S_F (float)(2.0 * 163.84 * 5.0 / 63.0)   /* 26.00635 */
#define LN_V          (-(64.0 / 63.0) * (64.0 / 63.0))
#define V_1           (float)exp(LN_V)           /* v                         */
#define V_2           (float)exp(2.0 * LN_V)     /* v^2 per-step multiplier   */

// Masked per-edge body. 8-tap window t_k = exp(-gamma*(delta-k*s)^2),
// anchored at k=0, ratios t_{k+1}/t_k = u*v^{2k+1}, u = exp(2*gamma*s*delta):
// t0 in [1e-22, 0.098] (no underflow), u <= e^14.4 (no overflow).
// Nearest dropped tap >= 2.5 spacings -> per-edge error <= ~1.6e-3;
// random-signed over ~7K survivors/graph -> sigma ~0.13 (measured absmax
// 0.125 in R7) vs threshold 0.995.
__device__ __forceinline__ void edge_body(
    float4v rs, float4v rd, const float4v* __restrict__ C4, int T,
    float* __restrict__ bins)
{
    const float dx = rd.x - rs.x;
    const float dy = rd.y - rs.y;
    const float dz = rd.z - rs.z;
    const float d2 = dx * dx + dy * dy + dz * dz + 1e-12f;
    if (d2 >= CUTOFF2_F) return;

    const float d = sqrtf(d2);
    const int sb = __float_as_int(rs.w);
    const int ts = sb & 0xFF;
    const int td = __float_as_int(rd.w) & 0xFF;
    const int lo = min(ts, td);
    const int hi = max(ts, td);
    const int base = (lo * T + hi) * NUM_RBF;

    const float c = d * INV_SPACING_F;
    int a0 = ((int)floorf(c - 1.5f)) & ~3;
    a0 = max(0, min(NUM_RBF - 8, a0));

    const float4v* w = C4 + ((base + a0) >> 2);
    const float4v w0 = w[0], w1 = w[1];

    const float delta = d - (float)a0 * SPACING_F;
    float t = __expf(-GAMMA_F * delta * delta);        // t0
    const float u = __expf(TWO_GAMMA_S_F * delta);
    float m = u * V_1;

    float acc = w0.x * t;
    t *= m;  m *= V_2;  acc += w0.y * t;
    t *= m;  m *= V_2;  acc += w0.z * t;
    t *= m;  m *= V_2;  acc += w0.w * t;
    t *= m;  m *= V_2;  acc += w1.x * t;
    t *= m;  m *= V_2;  acc += w1.y * t;
    t *= m;  m *= V_2;  acc += w1.z * t;
    t *= m;            acc += w1.w * t;

    const float fc = 0.5f * (__cosf(PI_OVER_C_F * d) + 1.0f);
    atomicAdd(&bins[(sb >> 8) & 0xFF], acc * fc);
}

__global__ __launch_bounds__(256) void edge_energy_kernel(
    const int*     __restrict__ edge_index,
    const float4v* __restrict__ rec,
    const float4v* __restrict__ C4,
    float*         __restrict__ partial,
    int E, int T)
{
    __shared__ float bins[N_GRAPHS];
    const int tid = threadIdx.x;
    for (int i = tid; i < N_GRAPHS; i += blockDim.x) bins[i] = 0.0f;
    __syncthreads();

    const int nfull  = E >> 2;
    const int stride = gridDim.x * blockDim.x;
    const int gid    = blockIdx.x * blockDim.x + tid;

    for (int q = gid; q < nfull; q += stride) {
        const int e0 = q << 2;
        // nontemporal: 12.8 MB once-streamed index data must not evict the
        // hot node-record / table working set from L2
        const int4v sv = __builtin_nontemporal_load(
            (const int4v*)(edge_index + e0));
        const int4v tv = __builtin_nontemporal_load(
            (const int4v*)(edge_index + E + e0));

        // 8 independent random 16B gathers in flight (compile-time register
        // slots — no scratch spill)
        const float4v rs0 = rec[sv.x], rd0 = rec[tv.x];
        const float4v rs1 = rec[sv.y], rd1 = rec[tv.y];
        const float4v rs2 = rec[sv.z], rd2 = rec[tv.z];
        const float4v rs3 = rec[sv.w], rd3 = rec[tv.w];

        edge_body(rs0, rd0, C4, T, bins);
        edge_body(rs1, rd1, C4, T, bins);
        edge_body(rs2, rd2, C4, T, bins);
        edge_body(rs3, rd3, C4, T, bins);
    }

    if (gid == 0) {                       // tail edges (E % 4)
        for (int e = nfull << 2; e < E; ++e) {
            const float4v rs = rec[edge_index[e]];
            const float4v rd = rec[edge_index[E + e]];
            edge_body(rs, rd, C4, T, bins);
        }
    }

    __syncthreads();
    for (int i = tid; i < N_GRAPHS; i += blockDim.x)
        partial[blockIdx.x * N_GRAPHS + i] = bins[i];
}

__global__ __launch_bounds__(256) void reduce_kernel(
    const float* __restrict__ partial, float* __restrict__ out, int nblocks)
{
    const int g = blockIdx.x;
    float s = 0.0f;
    for (int i = threadIdx.x; i < nblocks; i += blockDim.x)
        s += partial[i * N_GRAPHS + g];

    for (int off = 32; off > 0; off >>= 1)
        s += __shfl_down(s, off, 64);

    __shared__ float red[4];
    const int wave = threadIdx.x >> 6;
    const int lane = threadIdx.x & 63;
    if (lane == 0) red[wave] = s;
    __syncthreads();
    if (threadIdx.x == 0)
        out[g] = red[0] + red[1] + red[2] + red[3];
}

extern "C" void kernel_launch(void* const* d_in, const int* in_sizes, int n_in,
                              void* d_out, int out_size, void* d_ws, size_t ws_size,
                              hipStream_t stream) {
    const float* pos            = (const float*)d_in[0];
    const float* rbf_params     = (const float*)d_in[1];
    const float* radial_filters = (const float*)d_in[2];
    const int*   edge_index     = (const int*)d_in[3];
    const int*   atom_types     = (const int*)d_in[4];
    const int*   batch          = (const int*)d_in[5];
    float*       out            = (float*)d_out;

    const int E = in_sizes[3] / 2;
    const int N = in_sizes[4];
    int T = 1;
    while ((T + 1) * (T + 1) * NUM_RBF <= in_sizes[1]) ++T;
    const int tbl_elems = T * T * NUM_RBF;          // multiple of 4

    // workspace layout (256B aligned): [table | node recs | partials]
    float*   Ctab    = (float*)d_ws;
    float4v* recs    = (float4v*)((char*)d_ws + ((size_t)tbl_elems * 4 + 255) / 256 * 256);
    float*   partial = (float*)((char*)recs + (size_t)N * 16);

    const int nq = E >> 2;
    int nblocks = (nq + 255) / 256;                 // one quad per thread
    const size_t part_off = (size_t)((char*)partial - (char*)d_ws);
    const size_t avail = (ws_size > part_off) ? (ws_size - part_off) : 0;
    const int maxb = (int)(avail / (N_GRAPHS * sizeof(float)));
    if (nblocks > maxb) nblocks = maxb > 0 ? maxb : 1;
    if (nblocks < 1) nblocks = 1;

    const int pro_n = max(tbl_elems / 4, N);
    prologue_kernel<<<(pro_n + 255) / 256, 256, 0, stream>>>(
        (const float4v*)rbf_params, (const float4v*)radial_filters,
        (float4v*)Ctab, tbl_elems / 4, pos, atom_types, batch, recs, N);
    edge_energy_kernel<<<nblocks, 256, 0, stream>>>(
        edge_index, recs, (const float4v*)Ctab, partial, E, T);
    reduce_kernel<<<N_GRAPHS, 256, 0, stream>>>(partial, out, nblocks);
}